// Round 4
// baseline (215.902 us; speedup 1.0000x reference)
//
#include <hip/hip_runtime.h>
#include <cstdint>

typedef _Float16 half8 __attribute__((ext_vector_type(8)));
typedef __fp16 fp16x2 __attribute__((ext_vector_type(2)));
typedef float f32x4 __attribute__((ext_vector_type(4)));

// ws layout (halfs), per head 2048*64 = 131072 per tensor:
//  Kt: [head] fragment-order: frag(st=s/16, ks) at (st*2+ks)*512 + lane*8,
//      lane(q,l15) 8 halfs = K[16st+l15][32ks+8q+j]           (A-frag for S^T)
//  Vt: [head] sigma-fragment-order: frag(sc=s/32, ct) at (sc*4+ct)*512 + lane*8,
//      lane(q,l15) 8 halfs j = V[16ct+l15][32sc+4q+(j&3)+16(j>>2)]  (A-frag for O)
#define HSTRIDE 131072
#define KOFF    ((size_t)64 * HSTRIDE)
#define VOFF    ((size_t)128 * HSTRIDE)

__device__ __forceinline__ float fast_exp2(float x) {
    return __builtin_amdgcn_exp2f(x);
}

__device__ __forceinline__ uint32_t pkrtz(float a, float b) {
    fp16x2 h = __builtin_amdgcn_cvt_pkrtz(a, b);
    return __builtin_bit_cast(uint32_t, h);
}

// ---------------- prep: K transpose + V sigma-pack (unchanged) ----------------
__global__ __launch_bounds__(256) void prep_kernel(const float* __restrict__ qkv,
                                                   _Float16* __restrict__ ws)
{
    __shared__ float Lf[64 * 67];        // 16.75 KB (K branch only)

    const int tid  = threadIdx.x;
    const int lane = tid & 63;
    const int wave = tid >> 6;
    const int bid  = blockIdx.x;

    if (bid < 2048) {
        // ---- K ----
        const int head  = (bid >> 5) & 63;
        const int chunk = bid & 31;          // 64-wide s chunk
        const int b4 = head >> 4, h = head & 15;
        const float* src = qkv + (((size_t)(b4 * 3072 + h * 192 + 64)) << 11)
                         + chunk * 64;

#pragma unroll
        for (int k = 0; k < 4; ++k) {
            int idx = k * 256 + tid;
            int c = idx >> 4;
            int t4 = (idx & 15) << 2;
            float4 f = *(const float4*)&src[(((size_t)c) << 11) + t4];
            float* d = &Lf[c * 67 + t4];
            d[0] = f.x; d[1] = f.y; d[2] = f.z; d[3] = f.w;
        }
        __syncthreads();

        const int q = lane >> 4, l15 = lane & 15;
        const int scol = wave * 16 + l15;    // s within chunk
#pragma unroll
        for (int k = 0; k < 2; ++k) {
            uint32_t d[4];
#pragma unroll
            for (int j = 0; j < 4; ++j) {
                float a = Lf[(32 * k + 8 * q + 2 * j) * 67 + scol];
                float b = Lf[(32 * k + 8 * q + 2 * j + 1) * 67 + scol];
                d[j] = pkrtz(a, b);
            }
            size_t off = KOFF + (size_t)head * HSTRIDE
                       + (size_t)((((chunk * 4 + wave) * 2 + k) * 512) + lane * 8);
            *(uint4*)&ws[off] = make_uint4(d[0], d[1], d[2], d[3]);
        }
    } else {
        // ---- V ----
        const int vb = bid - 2048;
        const int head = vb >> 5, chunk = vb & 31;   // 64-s chunk
        const int b4 = head >> 4, h = head & 15;
        const float* src = qkv + (((size_t)(b4 * 3072 + h * 192 + 128)) << 11) + chunk * 64;
        const int q = lane >> 4, cl = lane & 15;
        const int c = wave * 16 + cl;
#pragma unroll
        for (int k = 0; k < 2; ++k) {
            const float* p = &src[((size_t)c << 11) + k * 32 + q * 4];
            float4 f0 = *(const float4*)&p[0];      // s = 4q..4q+3   (j=0..3)
            float4 f1 = *(const float4*)&p[16];     // s = 16+4q..+3  (j=4..7)
            size_t off = VOFF + (size_t)head * HSTRIDE
                       + (size_t)(((chunk * 2 + k) * 4 + wave) * 512 + lane * 8);
            *(uint4*)&ws[off] = make_uint4(pkrtz(f0.x, f0.y), pkrtz(f0.z, f0.w),
                                           pkrtz(f1.x, f1.y), pkrtz(f1.z, f1.w));
        }
    }
}

// ---------------- flash attention: NO LDS, NO BARRIERS, register dbuf ----------------
// Round-12 restructure. Rounds 9-11 proved intra-wave interleave is
// scheduler-refused and the per-tile barrier keeps the 2 co-resident blocks
// in-phase (MFMA 40% + VALU 37% SUM + 23% barrier dead time). Key structural
// fact: LDS had ZERO reuse -- each K/V fragment byte is consumed by exactly
// one lane-slot of one wave, and ws is already fragment-linear. So each lane
// loads its 16B fragment slice DIRECTLY from global (coalesced dwordx4),
// double-buffered in registers, 1 tile ahead. LDS, __syncthreads, waitcnt(0)
// drains and ds_reads all deleted; the 4 waves of a block are fully
// independent (t-split, per-row softmax) and free-run -> natural anti-phase
// between the 2 waves/SIMD overlaps one wave's exp cluster with the other's
// MFMA cluster. Tile granularity 32-s (64 iters) to fit the reg dbuf:
// ~240 VGPR (cap 256 via launch_bounds(256,2); occupancy grid-capped at
// 2 waves/SIMD anyway). Cross-wave K/V sharing moves LDS->L2 (~4x L2 read,
// well under the 34.5 TB/s ceiling; HBM bytes unchanged, L3 absorbs).
// Numerics: identical accumulation order per Oacc element as round-11.
__launch_bounds__(256, 2)
__global__ void attn_kernel(const float* __restrict__ qkv,
                            const _Float16* __restrict__ ws, float* __restrict__ out)
{
    const int tid  = threadIdx.x;
    const int lane = tid & 63;
    const int wave = tid >> 6;
    const int l15  = lane & 15;
    const int quad = lane >> 4;

    const int bid  = blockIdx.x;
    const int head = bid & 63;
    const int tblk = bid >> 6;
    const int T0   = tblk * 256;
    const int b4   = head >> 4;
    const int h    = head & 15;

    // per-lane fragment base pointers (lane*8 halfs = 16B slice)
    const _Float16* Kt = ws + KOFF + (size_t)head * HSTRIDE + lane * 8;
    const _Float16* Vt = ws + VOFF + (size_t)head * HSTRIDE + lane * 8;
    const float*    Qg = qkv + ((size_t)(b4 * 3072 + h * 192) << 11);
    const float kQ = 0.125f * 1.44269504088896340736f;  // scale^2 * log2(e)

    f32x4 Oacc[4][4];
#pragma unroll
    for (int ct = 0; ct < 4; ++ct)
#pragma unroll
        for (int nt = 0; nt < 4; ++nt) Oacc[ct][nt] = (f32x4)0.f;
    f32x4 Lacc[4];
#pragma unroll
    for (int nt = 0; nt < 4; ++nt) Lacc[nt] = (f32x4)0.f;
    const f32x4 fz = (f32x4)0.f;

    half8 ones;
#pragma unroll
    for (int j = 0; j < 8; ++j) ones[j] = (_Float16)1.0f;

    // K/V fragment register sets, ping-pong by tile parity (iter i -> set i&1).
    // Per 32-s tile i: K frags (4i + st*2 + ks)*512, V frags (4i + ct)*512.
    half8 kfA[2][2], kfB[2][2], vfA[4], vfB[4];

    // prologue: issue tile 0 (A) and tile 1 (B) loads before the Q gather;
    // Q-gather latency covers their arrival.
#pragma unroll
    for (int st = 0; st < 2; ++st)
#pragma unroll
        for (int ks = 0; ks < 2; ++ks) {
            kfA[st][ks] = *(const half8*)(Kt + (size_t)(0 * 4 + st * 2 + ks) * 512);
            kfB[st][ks] = *(const half8*)(Kt + (size_t)(1 * 4 + st * 2 + ks) * 512);
        }
#pragma unroll
    for (int ct = 0; ct < 4; ++ct) {
        vfA[ct] = *(const half8*)(Vt + (size_t)(0 * 4 + ct) * 512);
        vfB[ct] = *(const half8*)(Vt + (size_t)(1 * 4 + ct) * 512);
    }

    // Q B-frags: B[k=c=32ks+8q+j][n=t=16nt+l15], direct fp32 gather + scale + pack.
    half8 qb[4][2];
#pragma unroll
    for (int nt = 0; nt < 4; ++nt) {
        const int t = T0 + wave * 64 + nt * 16 + l15;
#pragma unroll
        for (int ks = 0; ks < 2; ++ks) {
            float f[8];
#pragma unroll
            for (int j = 0; j < 8; ++j)
                f[j] = Qg[((size_t)(ks * 32 + quad * 8 + j) << 11) + t];
            uint4 u = make_uint4(pkrtz(f[0] * kQ, f[1] * kQ), pkrtz(f[2] * kQ, f[3] * kQ),
                                 pkrtz(f[4] * kQ, f[5] * kQ), pkrtz(f[6] * kQ, f[7] * kQ));
            qb[nt][ks] = __builtin_bit_cast(half8, u);
        }
    }

    half8 pf[4];   // P B-frags of tile i, consumed by O(i) in body(i+1)

    // S(0) -> exp -> pf
    {
        f32x4 Sa[4], Sb[4];
#pragma unroll
        for (int nt = 0; nt < 4; ++nt) {
            f32x4 t0 = __builtin_amdgcn_mfma_f32_16x16x32_f16(kfA[0][0], qb[nt][0], fz, 0, 0, 0);
            Sa[nt]   = __builtin_amdgcn_mfma_f32_16x16x32_f16(kfA[0][1], qb[nt][1], t0, 0, 0, 0);
            f32x4 t1 = __builtin_amdgcn_mfma_f32_16x16x32_f16(kfA[1][0], qb[nt][0], fz, 0, 0, 0);
            Sb[nt]   = __builtin_amdgcn_mfma_f32_16x16x32_f16(kfA[1][1], qb[nt][1], t1, 0, 0, 0);
        }
#pragma unroll
        for (int nt = 0; nt < 4; ++nt) {
            uint4 u = make_uint4(pkrtz(fast_exp2(Sa[nt][0]), fast_exp2(Sa[nt][1])),
                                 pkrtz(fast_exp2(Sa[nt][2]), fast_exp2(Sa[nt][3])),
                                 pkrtz(fast_exp2(Sb[nt][0]), fast_exp2(Sb[nt][1])),
                                 pkrtz(fast_exp2(Sb[nt][2]), fast_exp2(Sb[nt][3])));
            pf[nt] = __builtin_bit_cast(half8, u);
        }
    }

    // body(i): [load kf(i+1) -> N] [O(i-1) consumes vfN(=vf(i-1)) + pf]
    //          [load vf(i+1) -> N] [S(i) from kfC] [exps -> pf]
    auto body = [&](int i, half8 (&kfC)[2][2], half8 (&kfN)[2][2],
                    half8 (&vfN)[4], bool pre) {
        if (pre) {
#pragma unroll
            for (int st = 0; st < 2; ++st)
#pragma unroll
                for (int ks = 0; ks < 2; ++ks)
                    kfN[st][ks] = *(const half8*)(Kt + (size_t)((i + 1) * 4 + st * 2 + ks) * 512);
        }
#pragma unroll
        for (int ct = 0; ct < 4; ++ct)
#pragma unroll
            for (int nt = 0; nt < 4; ++nt)
                Oacc[ct][nt] = __builtin_amdgcn_mfma_f32_16x16x32_f16(
                    vfN[ct], pf[nt], Oacc[ct][nt], 0, 0, 0);
#pragma unroll
        for (int nt = 0; nt < 4; ++nt)
            Lacc[nt] = __builtin_amdgcn_mfma_f32_16x16x32_f16(ones, pf[nt], Lacc[nt], 0, 0, 0);
        if (pre) {
#pragma unroll
            for (int ct = 0; ct < 4; ++ct)
                vfN[ct] = *(const half8*)(Vt + (size_t)((i + 1) * 4 + ct) * 512);
        }
        f32x4 Sa[4], Sb[4];
#pragma unroll
        for (int nt = 0; nt < 4; ++nt) {
            f32x4 t0 = __builtin_amdgcn_mfma_f32_16x16x32_f16(kfC[0][0], qb[nt][0], fz, 0, 0, 0);
            Sa[nt]   = __builtin_amdgcn_mfma_f32_16x16x32_f16(kfC[0][1], qb[nt][1], t0, 0, 0, 0);
            f32x4 t1 = __builtin_amdgcn_mfma_f32_16x16x32_f16(kfC[1][0], qb[nt][0], fz, 0, 0, 0);
            Sb[nt]   = __builtin_amdgcn_mfma_f32_16x16x32_f16(kfC[1][1], qb[nt][1], t1, 0, 0, 0);
        }
#pragma unroll
        for (int nt = 0; nt < 4; ++nt) {
            uint4 u = make_uint4(pkrtz(fast_exp2(Sa[nt][0]), fast_exp2(Sa[nt][1])),
                                 pkrtz(fast_exp2(Sa[nt][2]), fast_exp2(Sa[nt][3])),
                                 pkrtz(fast_exp2(Sb[nt][0]), fast_exp2(Sb[nt][1])),
                                 pkrtz(fast_exp2(Sb[nt][2]), fast_exp2(Sb[nt][3])));
            pf[nt] = __builtin_bit_cast(half8, u);
        }
    };

    // main loop: i = 1..62 (2x unrolled for static ping-pong), then i=63 no-load
    for (int m = 0; m < 31; ++m) {
        body(2 * m + 1, kfB, kfA, vfA, true);    // odd i: cur=B, N=A (holds i-1; reload i+1)
        body(2 * m + 2, kfA, kfB, vfB, true);    // even i: cur=A, N=B
    }
    body(63, kfB, kfA, vfA, false);

    // tail: O(63) with vf(63)=vfB and pf(63)
#pragma unroll
    for (int ct = 0; ct < 4; ++ct)
#pragma unroll
        for (int nt = 0; nt < 4; ++nt)
            Oacc[ct][nt] = __builtin_amdgcn_mfma_f32_16x16x32_f16(
                vfB[ct], pf[nt], Oacc[ct][nt], 0, 0, 0);
#pragma unroll
    for (int nt = 0; nt < 4; ++nt)
        Lacc[nt] = __builtin_amdgcn_mfma_f32_16x16x32_f16(ones, pf[nt], Lacc[nt], 0, 0, 0);

    // ---- epilogue: Lacc rows identical (A=ones) -> per-register scalar inv ----
    float inv[4];
#pragma unroll
    for (int nt = 0; nt < 4; ++nt) inv[nt] = 1.f / Lacc[nt][0];

    float* ob = out + (((size_t)(b4 * 1024 + h * 64)) << 11) + T0 + wave * 64;
#pragma unroll
    for (int ct = 0; ct < 4; ++ct)
#pragma unroll
        for (int nt = 0; nt < 4; ++nt) {
            f32x4 o = Oacc[ct][nt];
#pragma unroll
            for (int r = 0; r < 4; ++r)
                ob[((size_t)(ct * 16 + quad * 4 + r) << 11) + nt * 16 + l15] = o[r] * inv[nt];
        }
}

extern "C" void kernel_launch(void* const* d_in, const int* in_sizes, int n_in,
                              void* d_out, int out_size, void* d_ws, size_t ws_size,
                              hipStream_t stream) {
    const float* qkv = (const float*)d_in[0];
    float* out = (float*)d_out;
    _Float16* ws = (_Float16*)d_ws;
    prep_kernel<<<dim3(4096), dim3(256), 0, stream>>>(qkv, ws);
    attn_kernel<<<dim3(512), dim3(256), 0, stream>>>(qkv, ws, out);
}